// Round 5
// baseline (295.686 us; speedup 1.0000x reference)
//
#include <hip/hip_runtime.h>
#include <hip/hip_bf16.h>
#include <math.h>

#define B   2
#define TQ  1024
#define TKV 1024
#define D   1024
#define H   16
#define HD  64
#define P   64     // 2*SPAN
#define SPAN 32

#define NEG_INF (-3.0e38f)

typedef __attribute__((ext_vector_type(8))) short bf16x8;
typedef __attribute__((ext_vector_type(4))) float f32x4;
typedef unsigned short ushort_t;

// ---------------- workspace layout ----------------
// f32 region (float offsets):
static constexpr size_t QF_OFF   = 0;                         // 2M floats (q, f32)
static constexpr size_t CTX_OFF  = (size_t)2 * 1024 * 1024;   // 2M floats
static constexpr size_t C2P_OFF  = (size_t)4 * 1024 * 1024;   // 2M floats (pre-scaled)
static constexpr size_t P2C_OFF  = (size_t)6 * 1024 * 1024;   // 2M floats (pre-scaled)
static constexpr size_t RE_OFF   = (size_t)8 * 1024 * 1024;   // 64K floats
static constexpr size_t POSK_OFF = RE_OFF + (size_t)64 * 1024;
static constexpr size_t POSQ_OFF = POSK_OFF + (size_t)64 * 1024;
static constexpr size_t SHORT_BASE_BYTES = (POSQ_OFF + (size_t)64 * 1024) * 4;
// shorts region: KH, KL (row-major [token][D]), VTH, VTL ([bh][d][t]), each 2M shorts
static constexpr size_t KV_ELEMS = (size_t)2048 * 1024;

// split x into hi (bit-truncated bf16) + lo (RN bf16 of exact residual)
__device__ __forceinline__ void split2(float x, unsigned short& h, unsigned short& l) {
  unsigned int u = __float_as_uint(x);
  h = (unsigned short)(u >> 16);
  float r = x - __uint_as_float(u & 0xffff0000u);   // exact
  unsigned int v = __float_as_uint(r);
  v += 0x7fffu + ((v >> 16) & 1u);                  // RN-even
  l = (unsigned short)(v >> 16);
}

__device__ __forceinline__ unsigned short bf16rn(float x) {
  unsigned int v = __float_as_uint(x);
  v += 0x7fffu + ((v >> 16) & 1u);
  return (unsigned short)(v >> 16);
}

__device__ __forceinline__ float bf2f(unsigned short u) {
  return __uint_as_float(((unsigned int)u) << 16);
}

// ---------------- LayerNorm over rel_emb rows ----------------
__global__ __launch_bounds__(256) void ln_kernel(const float* __restrict__ x,
    const float* __restrict__ g, const float* __restrict__ bta, float* __restrict__ out) {
  const int row = blockIdx.x;
  const float* xr = x + (size_t)row * D;
  const int tid = threadIdx.x;
  __shared__ float red[4];
  float s = 0.f;
  for (int i = tid; i < D; i += 256) s += xr[i];
  #pragma unroll
  for (int off = 32; off; off >>= 1) s += __shfl_down(s, off);
  if ((tid & 63) == 0) red[tid >> 6] = s;
  __syncthreads();
  float mu = (red[0] + red[1] + red[2] + red[3]) * (1.0f / D);
  __syncthreads();
  float vs = 0.f;
  for (int i = tid; i < D; i += 256) { float dd = xr[i] - mu; vs += dd * dd; }
  #pragma unroll
  for (int off = 32; off; off >>= 1) vs += __shfl_down(vs, off);
  if ((tid & 63) == 0) red[tid >> 6] = vs;
  __syncthreads();
  float var = (red[0] + red[1] + red[2] + red[3]) * (1.0f / D);
  float rs = rsqrtf(var + 1e-5f);
  for (int i = tid; i < D; i += 256)
    out[(size_t)row * D + i] = (xr[i] - mu) * rs * g[i] + bta[i];
}

// ---------------- log-bucket position table ----------------
__global__ void tab_kernel(unsigned char* __restrict__ tab) {
  int i = blockIdx.x * 256 + threadIdx.x;
  if (i >= 2047) return;
  int d = i - 1023;
  int ad = d < 0 ? -d : d;
  int bucket;
  if (ad <= 16) {
    bucket = d;
  } else {
    double x = log((double)ad / 16.0) / log(127.0 / 16.0) * 15.0;
    double xr = floor(x + 0.5);
    double xc = (fabs(x - xr) < 1e-9) ? xr : ceil(x);
    int li = (int)xc + 16;
    bucket = (d > 0) ? li : -li;
  }
  int t = bucket + SPAN;
  t = t < 0 ? 0 : (t > 63 ? 63 : t);
  tab[i] = (unsigned char)t;
}

// ---------------- fp32 GEMM for the two 64-row pos projections (z-fused) ----------------
__global__ __launch_bounds__(256) void gemm_bias_pos(const float* __restrict__ A,
    const float* __restrict__ W0, const float* __restrict__ b0, float* __restrict__ C0,
    const float* __restrict__ W1, const float* __restrict__ b1, float* __restrict__ C1,
    int M, int N, int K) {
  const float* W = blockIdx.z ? W1 : W0;
  const float* bias = blockIdx.z ? b1 : b0;
  float* C = blockIdx.z ? C1 : C0;
  __shared__ __align__(16) float As[16][64];
  __shared__ __align__(16) float Ws[16][64];
  const int tid = threadIdx.x;
  const int bm = blockIdx.y * 64, bn = blockIdx.x * 64;
  const int tx = tid & 15, ty = tid >> 4;
  const int lm = tid >> 4, lk = tid & 15;
  float acc[4][4] = {};
  for (int k0 = 0; k0 < K; k0 += 16) {
    __syncthreads();
    #pragma unroll
    for (int r = 0; r < 4; r++) {
      As[lk][lm + 16 * r] = A[(size_t)(bm + lm + 16 * r) * K + k0 + lk];
      Ws[lk][lm + 16 * r] = W[(size_t)(bn + lm + 16 * r) * K + k0 + lk];
    }
    __syncthreads();
    #pragma unroll
    for (int kk = 0; kk < 16; kk++) {
      float4 a4 = *(const float4*)&As[kk][ty * 4];
      float4 b4 = *(const float4*)&Ws[kk][tx * 4];
      float av[4] = {a4.x, a4.y, a4.z, a4.w};
      float bv[4] = {b4.x, b4.y, b4.z, b4.w};
      #pragma unroll
      for (int i = 0; i < 4; i++)
        #pragma unroll
        for (int j = 0; j < 4; j++)
          acc[i][j] += av[i] * bv[j];
    }
  }
  #pragma unroll
  for (int i = 0; i < 4; i++) {
    int m = bm + ty * 4 + i;
    #pragma unroll
    for (int j = 0; j < 4; j++) {
      int n = bn + tx * 4 + j;
      C[(size_t)m * N + n] = acc[i][j] + bias[n];
    }
  }
}

// ---------------- split-bf16 MFMA GEMM: C[M,N] = A @ W^T + bias ----------------
// BM=128, BN=64, BK=32, 256 threads = 4 waves (2x2), wave tile 64x32.
// Epilogue by z: z=0 -> f32 row-major (Cf0); z=1 -> bf16 hi/lo row-major (KH/KL);
// z=2 -> bf16 hi/lo transposed [bh][d][t] (VH/VL).
__global__ __launch_bounds__(256) void gemm_split(
    const float* __restrict__ A0, const float* __restrict__ A1, const float* __restrict__ A2,
    const float* __restrict__ W0, const float* __restrict__ W1, const float* __restrict__ W2,
    const float* __restrict__ b0, const float* __restrict__ b1, const float* __restrict__ b2,
    float* __restrict__ Cf0,
    ushort_t* __restrict__ KH_, ushort_t* __restrict__ KL_,
    ushort_t* __restrict__ VH_, ushort_t* __restrict__ VL_,
    int M, int N, int K) {
  const int z = blockIdx.z;
  const float* A = (z == 0) ? A0 : (z == 1) ? A1 : A2;
  const float* W = (z == 0) ? W0 : (z == 1) ? W1 : W2;
  const float* bias = (z == 0) ? b0 : (z == 1) ? b1 : b2;

  __shared__ short sAhi[128 * 32];
  __shared__ short sAlo[128 * 32];
  __shared__ short sBhi[64 * 32];
  __shared__ short sBlo[64 * 32];

  const int t = threadIdx.x;
  const int bm = blockIdx.y * 128, bn = blockIdx.x * 64;
  const int wid = t >> 6, lane = t & 63;
  const int wr = wid >> 1, wc = wid & 1;
  const int fr = lane & 15, fo = (lane >> 4) * 8;

  f32x4 acc[4][2];
  #pragma unroll
  for (int i = 0; i < 4; i++)
    #pragma unroll
    for (int j = 0; j < 2; j++)
      acc[i][j] = (f32x4){0.f, 0.f, 0.f, 0.f};

  const int srow = t >> 3;          // 0..31
  const int scol = (t & 7) * 4;     // 0,4,..,28

  for (int k0 = 0; k0 < K; k0 += 32) {
    #pragma unroll
    for (int i = 0; i < 4; i++) {
      int row = srow + 32 * i;
      float4 a = *(const float4*)&A[(size_t)(bm + row) * K + k0 + scol];
      unsigned short h0, h1, h2, h3, l0, l1, l2, l3;
      split2(a.x, h0, l0); split2(a.y, h1, l1); split2(a.z, h2, l2); split2(a.w, h3, l3);
      *(short4*)&sAhi[row * 32 + scol] = make_short4((short)h0, (short)h1, (short)h2, (short)h3);
      *(short4*)&sAlo[row * 32 + scol] = make_short4((short)l0, (short)l1, (short)l2, (short)l3);
    }
    #pragma unroll
    for (int i = 0; i < 2; i++) {
      int row = srow + 32 * i;
      float4 a = *(const float4*)&W[(size_t)(bn + row) * K + k0 + scol];
      unsigned short h0, h1, h2, h3, l0, l1, l2, l3;
      split2(a.x, h0, l0); split2(a.y, h1, l1); split2(a.z, h2, l2); split2(a.w, h3, l3);
      *(short4*)&sBhi[row * 32 + scol] = make_short4((short)h0, (short)h1, (short)h2, (short)h3);
      *(short4*)&sBlo[row * 32 + scol] = make_short4((short)l0, (short)l1, (short)l2, (short)l3);
    }
    __syncthreads();

    bf16x8 ah[4], al[4], bh[2], bl[2];
    #pragma unroll
    for (int mf = 0; mf < 4; mf++) {
      int r = (wr * 64 + mf * 16 + fr) * 32 + fo;
      ah[mf] = *(const bf16x8*)&sAhi[r];
      al[mf] = *(const bf16x8*)&sAlo[r];
    }
    #pragma unroll
    for (int nf = 0; nf < 2; nf++) {
      int r = (wc * 32 + nf * 16 + fr) * 32 + fo;
      bh[nf] = *(const bf16x8*)&sBhi[r];
      bl[nf] = *(const bf16x8*)&sBlo[r];
    }
    #pragma unroll
    for (int mf = 0; mf < 4; mf++)
      #pragma unroll
      for (int nf = 0; nf < 2; nf++) {
        acc[mf][nf] = __builtin_amdgcn_mfma_f32_16x16x32_bf16(ah[mf], bh[nf], acc[mf][nf], 0, 0, 0);
        acc[mf][nf] = __builtin_amdgcn_mfma_f32_16x16x32_bf16(ah[mf], bl[nf], acc[mf][nf], 0, 0, 0);
        acc[mf][nf] = __builtin_amdgcn_mfma_f32_16x16x32_bf16(al[mf], bh[nf], acc[mf][nf], 0, 0, 0);
      }
    __syncthreads();
  }

  if (z == 0) {
    #pragma unroll
    for (int mf = 0; mf < 4; mf++) {
      int rbase = bm + wr * 64 + mf * 16 + (lane >> 4) * 4;
      #pragma unroll
      for (int nf = 0; nf < 2; nf++) {
        int col = bn + wc * 32 + nf * 16 + fr;
        float bb = bias[col];
        #pragma unroll
        for (int r = 0; r < 4; r++)
          Cf0[(size_t)(rbase + r) * N + col] = acc[mf][nf][r] + bb;
      }
    }
  } else if (z == 1) {
    // K: bf16 hi/lo row-major [token][D]
    #pragma unroll
    for (int mf = 0; mf < 4; mf++) {
      int rbase = bm + wr * 64 + mf * 16 + (lane >> 4) * 4;
      #pragma unroll
      for (int nf = 0; nf < 2; nf++) {
        int col = bn + wc * 32 + nf * 16 + fr;
        float bb = bias[col];
        #pragma unroll
        for (int r = 0; r < 4; r++) {
          unsigned short hh, ll;
          split2(acc[mf][nf][r] + bb, hh, ll);
          KH_[(size_t)(rbase + r) * N + col] = hh;
          KL_[(size_t)(rbase + r) * N + col] = ll;
        }
      }
    }
  } else {
    // V: bf16 hi/lo transposed [bh][d][t]
    #pragma unroll
    for (int mf = 0; mf < 4; mf++) {
      int m0 = bm + wr * 64 + mf * 16 + (lane >> 4) * 4;
      int bb2 = m0 >> 10, t0 = m0 & 1023;
      #pragma unroll
      for (int nf = 0; nf < 2; nf++) {
        int col = bn + wc * 32 + nf * 16 + fr;
        int hh = col >> 6, dd = col & 63;
        float bvv = bias[col];
        unsigned short h4[4], l4[4];
        #pragma unroll
        for (int r = 0; r < 4; r++) split2(acc[mf][nf][r] + bvv, h4[r], l4[r]);
        size_t dst = (((size_t)bb2 * 16 + hh) * 64 + dd) * 1024 + t0;
        *(short4*)&VH_[dst] = make_short4((short)h4[0], (short)h4[1], (short)h4[2], (short)h4[3]);
        *(short4*)&VL_[dst] = make_short4((short)l4[0], (short)l4[1], (short)l4[2], (short)l4[3]);
      }
    }
  }
}

// ---------------- rel projection (z0: q(f32).posk -> c2p; z1: k(bf16 hi/lo).posq -> p2c)
// outputs pre-scaled by 1/sqrt(128)
__global__ __launch_bounds__(256) void relproj_kernel(
    const float* __restrict__ X0, const float* __restrict__ P0, float* __restrict__ O0,
    const ushort_t* __restrict__ XH1, const ushort_t* __restrict__ XL1,
    const float* __restrict__ P1, float* __restrict__ O1) {
  const int z = blockIdx.z;
  const float* POS = z ? P1 : P0;
  float* out = z ? O1 : O0;
  const int bh = blockIdx.y, b = bh >> 4, h = bh & 15;
  const int t0 = blockIdx.x * 64;
  __shared__ __align__(16) float sx[64][68];
  __shared__ __align__(16) float sp[64][68];
  const int tid = threadIdx.x;
  for (int i = tid; i < 4096; i += 256) {
    int r = i >> 6, d = i & 63;
    size_t idx = ((size_t)b * TQ + t0 + r) * D + h * HD + d;
    sx[d][r] = z ? (bf2f(XH1[idx]) + bf2f(XL1[idx])) : X0[idx];
    sp[d][r] = POS[(size_t)r * D + h * HD + d];
  }
  __syncthreads();
  const int tx = tid & 15, ty = tid >> 4;
  float acc[4][4] = {};
  for (int d = 0; d < 64; d++) {
    float4 a4 = *(const float4*)&sx[d][ty * 4];
    float4 b4 = *(const float4*)&sp[d][tx * 4];
    float av[4] = {a4.x, a4.y, a4.z, a4.w};
    float bv[4] = {b4.x, b4.y, b4.z, b4.w};
    #pragma unroll
    for (int i = 0; i < 4; i++)
      #pragma unroll
      for (int j = 0; j < 4; j++)
        acc[i][j] += av[i] * bv[j];
  }
  const float inv_ps = 0.08838834764831845f;  // 1/sqrt(128)
  #pragma unroll
  for (int i = 0; i < 4; i++)
    #pragma unroll
    for (int j = 0; j < 4; j++)
      out[((size_t)bh * TQ + t0 + ty * 4 + i) * P + tx * 4 + j] = acc[i][j] * inv_ps;
}

// ---------------- MFMA flash attention with disentangled bias ----------------
// grid (TQ/64, B*H), 256 threads = 4 waves; wave w owns q rows q0+w*16..+15.
// K/V pre-split bf16 hi/lo in global; subtiled LDS layout [sub][fr] -> conflict-free;
// T14 async staging: load tile t+1 into regs during compute of tile t.
__global__ __launch_bounds__(256) void attn_mfma(
    const float* __restrict__ qb,
    const ushort_t* __restrict__ KH, const ushort_t* __restrict__ KL,
    const ushort_t* __restrict__ VTH, const ushort_t* __restrict__ VTL,
    const float* __restrict__ c2p, const float* __restrict__ p2c,
    const unsigned char* __restrict__ mask, const unsigned char* __restrict__ tab,
    float* __restrict__ ctx) {
  const int bh = blockIdx.y, b = bh >> 4, h = bh & 15;
  const int q0 = blockIdx.x * 64;
  const int tid = threadIdx.x;
  const int wid = tid >> 6, lane = tid & 63;
  const int g = lane >> 4, fr = lane & 15;

  // subtiled: sub = row16*8 + ks*4 + g  (row16 = mf or nf), slot = fr
  __shared__ __align__(16) short sKh[4096], sKl[4096], sVh[4096], sVl[4096];
  __shared__ __align__(16) float sc2p[64][68];
  __shared__ __align__(16) float sp2c[64][68];
  __shared__ unsigned char stab[2048];
  __shared__ unsigned char smask[64];

  // --- Q fragments from f32 (split once, kept in registers)
  bf16x8 qh[2], ql[2];
  {
    const int qrow = q0 + wid * 16 + fr;
    const float* qp = qb + ((size_t)b * TQ + qrow) * D + h * HD + g * 8;
    #pragma unroll
    for (int ks = 0; ks < 2; ks++) {
      float4 x0 = *(const float4*)(qp + ks * 32);
      float4 x1 = *(const float4*)(qp + ks * 32 + 4);
      float xs[8] = {x0.x, x0.y, x0.z, x0.w, x1.x, x1.y, x1.z, x1.w};
      bf16x8 th, tl;
      #pragma unroll
      for (int j = 0; j < 8; j++) {
        unsigned short hh, ll;
        split2(xs[j], hh, ll);
        th[j] = (short)hh; tl[j] = (short)ll;
      }
      qh[ks] = th; ql[ks] = tl;
    }
  }

  const int sr = tid >> 2;           // staging row 0..63
  const int sj0 = tid & 3;           // chunk base
  const int smf = sr >> 4, sfr = sr & 15;
  const int cb = (tid & 3) * 16;     // f32 staging col block

  // --- stage c2p tile (once, already scaled) + bucket table
  {
    const float* cp = c2p + ((size_t)bh * TQ + q0 + sr) * P + cb;
    #pragma unroll
    for (int cc = 0; cc < 4; cc++)
      *(float4*)&sc2p[sr][cb + cc * 4] = *(const float4*)(cp + cc * 4);
  }
  for (int i = tid; i < 2047; i += 256) stab[i] = tab[i];

  f32x4 acc[4];
  #pragma unroll
  for (int nf = 0; nf < 4; nf++) acc[nf] = (f32x4){0.f, 0.f, 0.f, 0.f};
  float m_run = NEG_INF, l_run = 0.f;

  const float inv_s = 0.07216878364870323f;  // 1/sqrt(192)
  const int qloc = wid * 16 + fr;

  // --- T14 prefetch registers
  bf16x8 rKh[2], rKl[2], rVh[2], rVl[2];
  float4 rP2c[4];
  unsigned char rmask = 0;

  auto load_tile = [&](int kt) {
    const int k0n = kt * 64;
    const size_t kbase = ((size_t)b * TKV + k0n + sr) * D + h * HD;
    const size_t vbase = ((size_t)bh * HD + sr) * TKV + k0n;
    const float* pp = p2c + ((size_t)bh * TKV + k0n + sr) * P + cb;
    #pragma unroll
    for (int u = 0; u < 2; u++) {
      int jj = sj0 + u * 4;
      rKh[u] = *(const bf16x8*)(KH + kbase + jj * 8);
      rKl[u] = *(const bf16x8*)(KL + kbase + jj * 8);
      rVh[u] = *(const bf16x8*)(VTH + vbase + jj * 8);
      rVl[u] = *(const bf16x8*)(VTL + vbase + jj * 8);
    }
    #pragma unroll
    for (int cc = 0; cc < 4; cc++) rP2c[cc] = *(const float4*)(pp + cc * 4);
    if (tid < 64) rmask = mask[(size_t)b * TKV + k0n + tid];
  };

  load_tile(0);

  for (int kt = 0; kt < TKV / 64; kt++) {
    const int k0 = kt * 64;
    __syncthreads();   // previous tile's readers done
    // --- ds_write phase (contiguous 1KB per wave per array)
    #pragma unroll
    for (int u = 0; u < 2; u++) {
      int jj = sj0 + u * 4;
      int sub = smf * 8 + (jj >> 2) * 4 + (jj & 3);
      *(bf16x8*)&sKh[sub * 128 + sfr * 8] = rKh[u];
      *(bf16x8*)&sKl[sub * 128 + sfr * 8] = rKl[u];
      *(bf16x8*)&sVh[sub * 128 + sfr * 8] = rVh[u];
      *(bf16x8*)&sVl[sub * 128 + sfr * 8] = rVl[u];
    }
    #pragma unroll
    for (int cc = 0; cc < 4; cc++) *(float4*)&sp2c[sr][cb + cc * 4] = rP2c[cc];
    if (tid < 64) smask[tid] = rmask;
    // --- issue next tile's global loads (overlap with compute below)
    if (kt + 1 < TKV / 64) load_tile(kt + 1);
    __syncthreads();

    // --- S^T = K.Q^T (split bf16: 3 terms)
    f32x4 st[4];
    #pragma unroll
    for (int mf = 0; mf < 4; mf++) st[mf] = (f32x4){0.f, 0.f, 0.f, 0.f};
    #pragma unroll
    for (int mf = 0; mf < 4; mf++) {
      #pragma unroll
      for (int ks = 0; ks < 2; ks++) {
        bf16x8 kh = *(const bf16x8*)&sKh[(mf * 8 + ks * 4 + g) * 128 + fr * 8];
        bf16x8 kl = *(const bf16x8*)&sKl[(mf * 8 + ks * 4 + g) * 128 + fr * 8];
        st[mf] = __builtin_amdgcn_mfma_f32_16x16x32_bf16(kh, qh[ks], st[mf], 0, 0, 0);
        st[mf] = __builtin_amdgcn_mfma_f32_16x16x32_bf16(kh, ql[ks], st[mf], 0, 0, 0);
        st[mf] = __builtin_amdgcn_mfma_f32_16x16x32_bf16(kl, qh[ks], st[mf], 0, 0, 0);
      }
    }

    // --- bias + mask + online softmax (q = fr per lane; kj = mf*16 + g*4 + rr)
    const int dq = q0 + qloc - k0 + 1023;
    const float* c2prow = &sc2p[qloc][0];
    float pv[4][4];
    float lmax = NEG_INF;
    #pragma unroll
    for (int mf = 0; mf < 4; mf++) {
      #pragma unroll
      for (int rr = 0; rr < 4; rr++) {
        int kj = mf * 16 + g * 4 + rr;
        int tbi = stab[dq - kj];
        float v = st[mf][rr] * inv_s + (c2prow[tbi] + sp2c[kj][tbi]);
        v = smask[kj] ? NEG_INF : v;
        pv[mf][rr] = v;
        lmax = fmaxf(lmax, v);
      }
    }
    lmax = fmaxf(lmax, __shfl_xor(lmax, 16));
    lmax = fmaxf(lmax, __shfl_xor(lmax, 32));
    float mnew = fmaxf(m_run, lmax);
    float fac = __expf(m_run - mnew);
    m_run = mnew;
    float psum = 0.f;
    #pragma unroll
    for (int mf = 0; mf < 4; mf++)
      #pragma unroll
      for (int rr = 0; rr < 4; rr++) {
        float e = __expf(pv[mf][rr] - mnew);
        pv[mf][rr] = e;
        psum += e;
      }
    psum += __shfl_xor(psum, 16);
    psum += __shfl_xor(psum, 32);
    l_run = l_run * fac + psum;

    // --- rescale ctx accumulators (acc rows are q = g*4 + rr)
    float facr[4];
    #pragma unroll
    for (int rr = 0; rr < 4; rr++) facr[rr] = __shfl(fac, g * 4 + rr);
    #pragma unroll
    for (int nf = 0; nf < 4; nf++)
      #pragma unroll
      for (int rr = 0; rr < 4; rr++) acc[nf][rr] *= facr[rr];

    // --- build P A-fragments via shfl gather
    bf16x8 pa[2];
    #pragma unroll
    for (int ks = 0; ks < 2; ks++) {
      bf16x8 t;
      #pragma unroll
      for (int j = 0; j < 8; j++) {
        int src = ((2 * (g & 1) + (j >> 2)) << 4) | fr;
        float v0 = __shfl(pv[2 * ks][j & 3], src);
        float v1 = __shfl(pv[2 * ks + 1][j & 3], src);
        float pvv = (g >> 1) ? v1 : v0;
        t[j] = (short)bf16rn(pvv);
      }
      pa[ks] = t;
    }

    // --- ctx += P.V (V split hi+lo)
    #pragma unroll
    for (int nf = 0; nf < 4; nf++) {
      #pragma unroll
      for (int ks = 0; ks < 2; ks++) {
        bf16x8 vh = *(const bf16x8*)&sVh[(nf * 8 + ks * 4 + g) * 128 + fr * 8];
        bf16x8 vl = *(const bf16x8*)&sVl[(nf * 8 + ks * 4 + g) * 128 + fr * 8];
        acc[nf] = __builtin_amdgcn_mfma_f32_16x16x32_bf16(pa[ks], vh, acc[nf], 0, 0, 0);
        acc[nf] = __builtin_amdgcn_mfma_f32_16x16x32_bf16(pa[ks], vl, acc[nf], 0, 0, 0);
      }
    }
  }

  // --- epilogue
  float invl[4];
  #pragma unroll
  for (int rr = 0; rr < 4; rr++) invl[rr] = 1.0f / __shfl(l_run, g * 4 + rr);
  #pragma unroll
  for (int nf = 0; nf < 4; nf++) {
    #pragma unroll
    for (int rr = 0; rr < 4; rr++) {
      int qrow = q0 + wid * 16 + g * 4 + rr;
      int dcol = h * HD + nf * 16 + fr;
      ctx[((size_t)b * TQ + qrow) * D + dcol] = acc[nf][rr] * invl[rr];
    }
  }
}

extern "C" void kernel_launch(void* const* d_in, const int* in_sizes, int n_in,
                              void* d_out, int out_size, void* d_ws, size_t ws_size,
                              hipStream_t stream) {
  const float* query = (const float*)d_in[0];
  const float* kv    = (const float*)d_in[1];
  const float* Wq  = (const float*)d_in[2];   const float* bq  = (const float*)d_in[3];
  const float* Wk  = (const float*)d_in[4];   const float* bk  = (const float*)d_in[5];
  const float* Wv  = (const float*)d_in[6];   const float* bv  = (const float*)d_in[7];
  const float* Wo  = (const float*)d_in[8];   const float* bo  = (const float*)d_in[9];
  const float* Wpk = (const float*)d_in[10];  const float* bpk = (const float*)d_in[11];
  const float* Wpq = (const float*)d_in[12];  const float* bpq = (const float*)d_in[13];
  const float* rel_emb = (const float*)d_in[14];
  const float* ln_g = (const float*)d_in[15];
  const float* ln_b = (const float*)d_in[16];
  const unsigned char* amask = (const unsigned char*)d_in[17];

  float* ws = (float*)d_ws;
  float* qbuf   = ws + QF_OFF;
  float* ctxbuf = ws + CTX_OFF;
  float* c2pbuf = ws + C2P_OFF;
  float* p2cbuf = ws + P2C_OFF;
  float* rebuf  = ws + RE_OFF;
  float* poskbuf = ws + POSK_OFF;
  float* posqbuf = ws + POSQ_OFF;
  ushort_t* KH  = (ushort_t*)((char*)d_ws + SHORT_BASE_BYTES);
  ushort_t* KL  = KH + KV_ELEMS;
  ushort_t* VTH = KL + KV_ELEMS;
  ushort_t* VTL = VTH + KV_ELEMS;
  unsigned char* tab = (unsigned char*)(VTL + KV_ELEMS);

  // 1. LayerNorm of rel_emb + bucket table
  ln_kernel<<<64, 256, 0, stream>>>(rel_emb, ln_g, ln_b, rebuf);
  tab_kernel<<<8, 256, 0, stream>>>(tab);
  // 2. positional projections (64 x 1024 @ 1024^2), z-fused
  gemm_bias_pos<<<dim3(16, 1, 2), 256, 0, stream>>>(rebuf, Wpk, bpk, poskbuf,
                                                    Wpq, bpq, posqbuf, 64, 1024, 1024);
  // 3. Q/K/V projections fused; Q f32, K bf16 hi/lo, V bf16 hi/lo transposed
  gemm_split<<<dim3(16, 16, 3), 256, 0, stream>>>(
      query, kv, kv,  Wq, Wk, Wv,  bq, bk, bv,
      qbuf, KH, KL, VTH, VTL, 2048, 1024, 1024);
  // 4. c2p = q . pos_k, p2c = k . pos_q (z-fused, pre-scaled by 1/sqrt(128))
  relproj_kernel<<<dim3(16, 32, 2), 256, 0, stream>>>(
      qbuf, poskbuf, c2pbuf, KH, KL, posqbuf, p2cbuf);
  // 5. MFMA flash attention
  attn_mfma<<<dim3(16, 32), 256, 0, stream>>>(qbuf, KH, KL, VTH, VTL,
                                              c2pbuf, p2cbuf, amask, tab, ctxbuf);
  // 6. output projection -> d_out (z=0 f32 path)
  gemm_split<<<dim3(16, 16, 1), 256, 0, stream>>>(
      ctxbuf, ctxbuf, ctxbuf,  Wo, Wo, Wo,  bo, bo, bo,
      (float*)d_out, nullptr, nullptr, nullptr, nullptr, 2048, 1024, 1024);
}

// Round 6
// 282.971 us; speedup vs baseline: 1.0449x; 1.0449x over previous
//
#include <hip/hip_runtime.h>
#include <hip/hip_bf16.h>
#include <math.h>

#define B   2
#define TQ  1024
#define TKV 1024
#define D   1024
#define H   16
#define HD  64
#define P   64     // 2*SPAN
#define SPAN 32

#define NEG_INF (-3.0e38f)

typedef __attribute__((ext_vector_type(8))) short bf16x8;
typedef __attribute__((ext_vector_type(4))) float f32x4;
typedef unsigned short ushort_t;

// ---------------- workspace layout ----------------
// f32 region (float offsets):
static constexpr size_t QF_OFF   = 0;                          // 2M floats
static constexpr size_t CTX_OFF  = (size_t)2 * 1024 * 1024;    // 2M floats
static constexpr size_t RE_OFF   = (size_t)4 * 1024 * 1024;    // 64K floats
static constexpr size_t POSK_OFF = RE_OFF + (size_t)64 * 1024;
static constexpr size_t POSQ_OFF = POSK_OFF + (size_t)64 * 1024;
static constexpr size_t FLOATS_END = POSQ_OFF + (size_t)64 * 1024;
static constexpr size_t SHORT_BASE_BYTES = FLOATS_END * 4;
// ushort region (ushort offsets from SHORT_BASE):
static constexpr size_t C2P_S = 0;                             // 2M (bf16, pre-scaled)
static constexpr size_t P2C_S = (size_t)2 * 1024 * 1024;       // 2M
static constexpr size_t KH_S  = (size_t)4 * 1024 * 1024;       // 2M each
static constexpr size_t KL_S  = (size_t)6 * 1024 * 1024;
static constexpr size_t VTH_S = (size_t)8 * 1024 * 1024;
static constexpr size_t VTL_S = (size_t)10 * 1024 * 1024;
static constexpr size_t TAB_OFF_BYTES = SHORT_BASE_BYTES + (size_t)12 * 1024 * 1024 * 2;

// split x into hi (bit-truncated bf16) + lo (RN bf16 of exact residual)
__device__ __forceinline__ void split2(float x, unsigned short& h, unsigned short& l) {
  unsigned int u = __float_as_uint(x);
  h = (unsigned short)(u >> 16);
  float r = x - __uint_as_float(u & 0xffff0000u);   // exact
  unsigned int v = __float_as_uint(r);
  v += 0x7fffu + ((v >> 16) & 1u);                  // RN-even
  l = (unsigned short)(v >> 16);
}

__device__ __forceinline__ unsigned short bf16rn(float x) {
  unsigned int v = __float_as_uint(x);
  v += 0x7fffu + ((v >> 16) & 1u);
  return (unsigned short)(v >> 16);
}

__device__ __forceinline__ float bf2f(unsigned short u) {
  return __uint_as_float(((unsigned int)u) << 16);
}

// ---------------- LayerNorm over rel_emb rows ----------------
__global__ __launch_bounds__(256) void ln_kernel(const float* __restrict__ x,
    const float* __restrict__ g, const float* __restrict__ bta, float* __restrict__ out) {
  const int row = blockIdx.x;
  const float* xr = x + (size_t)row * D;
  const int tid = threadIdx.x;
  __shared__ float red[4];
  float s = 0.f;
  for (int i = tid; i < D; i += 256) s += xr[i];
  #pragma unroll
  for (int off = 32; off; off >>= 1) s += __shfl_down(s, off);
  if ((tid & 63) == 0) red[tid >> 6] = s;
  __syncthreads();
  float mu = (red[0] + red[1] + red[2] + red[3]) * (1.0f / D);
  __syncthreads();
  float vs = 0.f;
  for (int i = tid; i < D; i += 256) { float dd = xr[i] - mu; vs += dd * dd; }
  #pragma unroll
  for (int off = 32; off; off >>= 1) vs += __shfl_down(vs, off);
  if ((tid & 63) == 0) red[tid >> 6] = vs;
  __syncthreads();
  float var = (red[0] + red[1] + red[2] + red[3]) * (1.0f / D);
  float rs = rsqrtf(var + 1e-5f);
  for (int i = tid; i < D; i += 256)
    out[(size_t)row * D + i] = (xr[i] - mu) * rs * g[i] + bta[i];
}

// ---------------- log-bucket position table ----------------
__global__ void tab_kernel(unsigned char* __restrict__ tab) {
  int i = blockIdx.x * 256 + threadIdx.x;
  if (i >= 2047) return;
  int d = i - 1023;
  int ad = d < 0 ? -d : d;
  int bucket;
  if (ad <= 16) {
    bucket = d;
  } else {
    double x = log((double)ad / 16.0) / log(127.0 / 16.0) * 15.0;
    double xr = floor(x + 0.5);
    double xc = (fabs(x - xr) < 1e-9) ? xr : ceil(x);
    int li = (int)xc + 16;
    bucket = (d > 0) ? li : -li;
  }
  int t = bucket + SPAN;
  t = t < 0 ? 0 : (t > 63 ? 63 : t);
  tab[i] = (unsigned char)t;
}

// ---------------- fp32 GEMM for the two 64-row pos projections (z-fused) ----------------
__global__ __launch_bounds__(256) void gemm_bias_pos(const float* __restrict__ A,
    const float* __restrict__ W0, const float* __restrict__ b0, float* __restrict__ C0,
    const float* __restrict__ W1, const float* __restrict__ b1, float* __restrict__ C1,
    int M, int N, int K) {
  const float* W = blockIdx.z ? W1 : W0;
  const float* bias = blockIdx.z ? b1 : b0;
  float* C = blockIdx.z ? C1 : C0;
  __shared__ __align__(16) float As[16][64];
  __shared__ __align__(16) float Ws[16][64];
  const int tid = threadIdx.x;
  const int bm = blockIdx.y * 64, bn = blockIdx.x * 64;
  const int tx = tid & 15, ty = tid >> 4;
  const int lm = tid >> 4, lk = tid & 15;
  float acc[4][4] = {};
  for (int k0 = 0; k0 < K; k0 += 16) {
    __syncthreads();
    #pragma unroll
    for (int r = 0; r < 4; r++) {
      As[lk][lm + 16 * r] = A[(size_t)(bm + lm + 16 * r) * K + k0 + lk];
      Ws[lk][lm + 16 * r] = W[(size_t)(bn + lm + 16 * r) * K + k0 + lk];
    }
    __syncthreads();
    #pragma unroll
    for (int kk = 0; kk < 16; kk++) {
      float4 a4 = *(const float4*)&As[kk][ty * 4];
      float4 b4 = *(const float4*)&Ws[kk][tx * 4];
      float av[4] = {a4.x, a4.y, a4.z, a4.w};
      float bv[4] = {b4.x, b4.y, b4.z, b4.w};
      #pragma unroll
      for (int i = 0; i < 4; i++)
        #pragma unroll
        for (int j = 0; j < 4; j++)
          acc[i][j] += av[i] * bv[j];
    }
  }
  #pragma unroll
  for (int i = 0; i < 4; i++) {
    int m = bm + ty * 4 + i;
    #pragma unroll
    for (int j = 0; j < 4; j++) {
      int n = bn + tx * 4 + j;
      C[(size_t)m * N + n] = acc[i][j] + bias[n];
    }
  }
}

// ---------------- split-bf16 MFMA GEMM: C[M,N] = A @ W^T + bias ----------------
// BM=128, BN=64, BK=32, 256 threads = 4 waves (2x2), wave tile 64x32.
// Epilogue by z: z=0 -> f32 row-major; z=1 -> bf16 hi/lo row-major (K);
// z=2 -> bf16 hi/lo transposed [bh][d][t] (V).
__global__ __launch_bounds__(256) void gemm_split(
    const float* __restrict__ A0, const float* __restrict__ A1, const float* __restrict__ A2,
    const float* __restrict__ W0, const float* __restrict__ W1, const float* __restrict__ W2,
    const float* __restrict__ b0, const float* __restrict__ b1, const float* __restrict__ b2,
    float* __restrict__ Cf0,
    ushort_t* __restrict__ KH_, ushort_t* __restrict__ KL_,
    ushort_t* __restrict__ VH_, ushort_t* __restrict__ VL_,
    int M, int N, int K) {
  const int z = blockIdx.z;
  const float* A = (z == 0) ? A0 : (z == 1) ? A1 : A2;
  const float* W = (z == 0) ? W0 : (z == 1) ? W1 : W2;
  const float* bias = (z == 0) ? b0 : (z == 1) ? b1 : b2;

  __shared__ short sAhi[128 * 32];
  __shared__ short sAlo[128 * 32];
  __shared__ short sBhi[64 * 32];
  __shared__ short sBlo[64 * 32];

  const int t = threadIdx.x;
  const int bm = blockIdx.y * 128, bn = blockIdx.x * 64;
  const int wid = t >> 6, lane = t & 63;
  const int wr = wid >> 1, wc = wid & 1;
  const int fr = lane & 15, fo = (lane >> 4) * 8;

  f32x4 acc[4][2];
  #pragma unroll
  for (int i = 0; i < 4; i++)
    #pragma unroll
    for (int j = 0; j < 2; j++)
      acc[i][j] = (f32x4){0.f, 0.f, 0.f, 0.f};

  const int srow = t >> 3;          // 0..31
  const int scol = (t & 7) * 4;     // 0,4,..,28

  for (int k0 = 0; k0 < K; k0 += 32) {
    #pragma unroll
    for (int i = 0; i < 4; i++) {
      int row = srow + 32 * i;
      float4 a = *(const float4*)&A[(size_t)(bm + row) * K + k0 + scol];
      unsigned short h0, h1, h2, h3, l0, l1, l2, l3;
      split2(a.x, h0, l0); split2(a.y, h1, l1); split2(a.z, h2, l2); split2(a.w, h3, l3);
      *(short4*)&sAhi[row * 32 + scol] = make_short4((short)h0, (short)h1, (short)h2, (short)h3);
      *(short4*)&sAlo[row * 32 + scol] = make_short4((short)l0, (short)l1, (short)l2, (short)l3);
    }
    #pragma unroll
    for (int i = 0; i < 2; i++) {
      int row = srow + 32 * i;
      float4 a = *(const float4*)&W[(size_t)(bn + row) * K + k0 + scol];
      unsigned short h0, h1, h2, h3, l0, l1, l2, l3;
      split2(a.x, h0, l0); split2(a.y, h1, l1); split2(a.z, h2, l2); split2(a.w, h3, l3);
      *(short4*)&sBhi[row * 32 + scol] = make_short4((short)h0, (short)h1, (short)h2, (short)h3);
      *(short4*)&sBlo[row * 32 + scol] = make_short4((short)l0, (short)l1, (short)l2, (short)l3);
    }
    __syncthreads();

    bf16x8 ah[4], al[4], bh[2], bl[2];
    #pragma unroll
    for (int mf = 0; mf < 4; mf++) {
      int r = (wr * 64 + mf * 16 + fr) * 32 + fo;
      ah[mf] = *(const bf16x8*)&sAhi[r];
      al[mf] = *(const bf16x8*)&sAlo[r];
    }
    #pragma unroll
    for (int nf = 0; nf < 2; nf++) {
      int r = (wc * 32 + nf * 16 + fr) * 32 + fo;
      bh[nf] = *(const bf16x8*)&sBhi[r];
      bl[nf] = *(const bf16x8*)&sBlo[r];
    }
    #pragma unroll
    for (int mf = 0; mf < 4; mf++)
      #pragma unroll
      for (int nf = 0; nf < 2; nf++) {
        acc[mf][nf] = __builtin_amdgcn_mfma_f32_16x16x32_bf16(ah[mf], bh[nf], acc[mf][nf], 0, 0, 0);
        acc[mf][nf] = __builtin_amdgcn_mfma_f32_16x16x32_bf16(ah[mf], bl[nf], acc[mf][nf], 0, 0, 0);
        acc[mf][nf] = __builtin_amdgcn_mfma_f32_16x16x32_bf16(al[mf], bh[nf], acc[mf][nf], 0, 0, 0);
      }
    __syncthreads();
  }

  if (z == 0) {
    #pragma unroll
    for (int mf = 0; mf < 4; mf++) {
      int rbase = bm + wr * 64 + mf * 16 + (lane >> 4) * 4;
      #pragma unroll
      for (int nf = 0; nf < 2; nf++) {
        int col = bn + wc * 32 + nf * 16 + fr;
        float bb = bias[col];
        #pragma unroll
        for (int r = 0; r < 4; r++)
          Cf0[(size_t)(rbase + r) * N + col] = acc[mf][nf][r] + bb;
      }
    }
  } else if (z == 1) {
    #pragma unroll
    for (int mf = 0; mf < 4; mf++) {
      int rbase = bm + wr * 64 + mf * 16 + (lane >> 4) * 4;
      #pragma unroll
      for (int nf = 0; nf < 2; nf++) {
        int col = bn + wc * 32 + nf * 16 + fr;
        float bb = bias[col];
        #pragma unroll
        for (int r = 0; r < 4; r++) {
          unsigned short hh, ll;
          split2(acc[mf][nf][r] + bb, hh, ll);
          KH_[(size_t)(rbase + r) * N + col] = hh;
          KL_[(size_t)(rbase + r) * N + col] = ll;
        }
      }
    }
  } else {
    #pragma unroll
    for (int mf = 0; mf < 4; mf++) {
      int m0 = bm + wr * 64 + mf * 16 + (lane >> 4) * 4;
      int bb2 = m0 >> 10, t0 = m0 & 1023;
      #pragma unroll
      for (int nf = 0; nf < 2; nf++) {
        int col = bn + wc * 32 + nf * 16 + fr;
        int hh = col >> 6, dd = col & 63;
        float bvv = bias[col];
        unsigned short h4[4], l4[4];
        #pragma unroll
        for (int r = 0; r < 4; r++) split2(acc[mf][nf][r] + bvv, h4[r], l4[r]);
        size_t dst = (((size_t)bb2 * 16 + hh) * 64 + dd) * 1024 + t0;
        *(short4*)&VH_[dst] = make_short4((short)h4[0], (short)h4[1], (short)h4[2], (short)h4[3]);
        *(short4*)&VL_[dst] = make_short4((short)l4[0], (short)l4[1], (short)l4[2], (short)l4[3]);
      }
    }
  }
}

// ---------------- rel projection -> bf16 outputs pre-scaled by 1/sqrt(128) ----------------
// z0: q(f32) . pos_k -> c2p; z1: k(bf16 hi/lo) . pos_q -> p2c
__global__ __launch_bounds__(256) void relproj_kernel(
    const float* __restrict__ X0, const float* __restrict__ P0, ushort_t* __restrict__ O0,
    const ushort_t* __restrict__ XH1, const ushort_t* __restrict__ XL1,
    const float* __restrict__ P1, ushort_t* __restrict__ O1) {
  const int z = blockIdx.z;
  const float* POS = z ? P1 : P0;
  ushort_t* out = z ? O1 : O0;
  const int bh = blockIdx.y, b = bh >> 4, h = bh & 15;
  const int t0 = blockIdx.x * 64;
  __shared__ __align__(16) float sx[64][68];
  __shared__ __align__(16) float sp[64][68];
  const int tid = threadIdx.x;
  for (int i = tid; i < 4096; i += 256) {
    int r = i >> 6, d = i & 63;
    size_t idx = ((size_t)b * TQ + t0 + r) * D + h * HD + d;
    sx[d][r] = z ? (bf2f(XH1[idx]) + bf2f(XL1[idx])) : X0[idx];
    sp[d][r] = POS[(size_t)r * D + h * HD + d];
  }
  __syncthreads();
  const int tx = tid & 15, ty = tid >> 4;
  float acc[4][4] = {};
  for (int d = 0; d < 64; d++) {
    float4 a4 = *(const float4*)&sx[d][ty * 4];
    float4 b4 = *(const float4*)&sp[d][tx * 4];
    float av[4] = {a4.x, a4.y, a4.z, a4.w};
    float bv[4] = {b4.x, b4.y, b4.z, b4.w};
    #pragma unroll
    for (int i = 0; i < 4; i++)
      #pragma unroll
      for (int j = 0; j < 4; j++)
        acc[i][j] += av[i] * bv[j];
  }
  const float inv_ps = 0.08838834764831845f;  // 1/sqrt(128)
  #pragma unroll
  for (int i = 0; i < 4; i++)
    #pragma unroll
    for (int j = 0; j < 4; j++)
      out[((size_t)bh * TQ + t0 + ty * 4 + i) * P + tx * 4 + j] = bf16rn(acc[i][j] * inv_ps);
}

// ---------------- MFMA flash attention with disentangled bias ----------------
// grid 512 blocks (XCD-swizzled: 16 q-blocks of each bh on one XCD), 4 waves.
// K/V pre-split bf16 hi/lo; bias tiles bf16; LDS ~53KB -> 3 blocks/CU.
__global__ __launch_bounds__(256) void attn_mfma(
    const float* __restrict__ qb,
    const ushort_t* __restrict__ KH, const ushort_t* __restrict__ KL,
    const ushort_t* __restrict__ VTH, const ushort_t* __restrict__ VTL,
    const ushort_t* __restrict__ c2p, const ushort_t* __restrict__ p2c,
    const unsigned char* __restrict__ mask, const unsigned char* __restrict__ tab,
    float* __restrict__ ctx) {
  // --- XCD swizzle: flat dispatch id -> (bh, q-block) with 16 q-blocks/bh per XCD
  const int flat = blockIdx.y * gridDim.x + blockIdx.x;   // 0..511
  const int nid = (flat & 7) * 64 + (flat >> 3);          // bijective (512 % 8 == 0)
  const int bh = nid >> 4, b = bh >> 4, h = bh & 15;
  const int q0 = (nid & 15) * 64;

  const int tid = threadIdx.x;
  const int wid = tid >> 6, lane = tid & 63;
  const int g = lane >> 4, fr = lane & 15;

  // subtiled K/V: sub = row16*8 + ks*4 + g, slot = fr (16B each)
  __shared__ __align__(16) short sKh[4096], sKl[4096], sVh[4096], sVl[4096];
  __shared__ __align__(16) ushort_t sc2p[64][72];
  __shared__ __align__(16) ushort_t sp2c[64][72];
  __shared__ unsigned char stab[2048];
  __shared__ unsigned char smask[64];

  // --- Q fragments from f32 (split once, kept in registers)
  bf16x8 qh[2], ql[2];
  {
    const int qrow = q0 + wid * 16 + fr;
    const float* qp = qb + ((size_t)b * TQ + qrow) * D + h * HD + g * 8;
    #pragma unroll
    for (int ks = 0; ks < 2; ks++) {
      float4 x0 = *(const float4*)(qp + ks * 32);
      float4 x1 = *(const float4*)(qp + ks * 32 + 4);
      float xs[8] = {x0.x, x0.y, x0.z, x0.w, x1.x, x1.y, x1.z, x1.w};
      bf16x8 th, tl;
      #pragma unroll
      for (int j = 0; j < 8; j++) {
        unsigned short hh, ll;
        split2(xs[j], hh, ll);
        th[j] = (short)hh; tl[j] = (short)ll;
      }
      qh[ks] = th; ql[ks] = tl;
    }
  }

  const int sr = tid >> 2;           // staging row 0..63
  const int sj0 = tid & 3;           // chunk base
  const int smf = sr >> 4, sfr = sr & 15;
  const int cb = (tid & 3) * 16;     // bias staging col block (16 ushorts)

  // --- stage c2p tile (once, bf16, pre-scaled) + bucket table
  {
    const ushort_t* cp = c2p + ((size_t)bh * TQ + q0 + sr) * P + cb;
    *(bf16x8*)&sc2p[sr][cb]     = *(const bf16x8*)cp;
    *(bf16x8*)&sc2p[sr][cb + 8] = *(const bf16x8*)(cp + 8);
  }
  for (int i = tid; i < 2047; i += 256) stab[i] = tab[i];

  f32x4 acc[4];
  #pragma unroll
  for (int nf = 0; nf < 4; nf++) acc[nf] = (f32x4){0.f, 0.f, 0.f, 0.f};
  float m_run = NEG_INF, l_run = 0.f;

  const float inv_s = 0.07216878364870323f;  // 1/sqrt(192)
  const int qloc = wid * 16 + fr;

  // --- T14 prefetch registers
  bf16x8 rKh[2], rKl[2], rVh[2], rVl[2], rP0, rP1;
  unsigned char rmask = 0;

  auto load_tile = [&](int kt) {
    const int k0n = kt * 64;
    const size_t kbase = ((size_t)b * TKV + k0n + sr) * D + h * HD;
    const size_t vbase = ((size_t)bh * HD + sr) * TKV + k0n;
    const ushort_t* pp = p2c + ((size_t)bh * TKV + k0n + sr) * P + cb;
    #pragma unroll
    for (int u = 0; u < 2; u++) {
      int jj = sj0 + u * 4;
      rKh[u] = *(const bf16x8*)(KH + kbase + jj * 8);
      rKl[u] = *(const bf16x8*)(KL + kbase + jj * 8);
      rVh[u] = *(const bf16x8*)(VTH + vbase + jj * 8);
      rVl[u] = *(const bf16x8*)(VTL + vbase + jj * 8);
    }
    rP0 = *(const bf16x8*)pp;
    rP1 = *(const bf16x8*)(pp + 8);
    if (tid < 64) rmask = mask[(size_t)b * TKV + k0n + tid];
  };

  load_tile(0);

  for (int kt = 0; kt < TKV / 64; kt++) {
    const int k0 = kt * 64;
    __syncthreads();   // previous tile's readers done
    // --- ds_write phase
    #pragma unroll
    for (int u = 0; u < 2; u++) {
      int jj = sj0 + u * 4;
      int sub = smf * 8 + (jj >> 2) * 4 + (jj & 3);
      *(bf16x8*)&sKh[sub * 128 + sfr * 8] = rKh[u];
      *(bf16x8*)&sKl[sub * 128 + sfr * 8] = rKl[u];
      *(bf16x8*)&sVh[sub * 128 + sfr * 8] = rVh[u];
      *(bf16x8*)&sVl[sub * 128 + sfr * 8] = rVl[u];
    }
    *(bf16x8*)&sp2c[sr][cb]     = rP0;
    *(bf16x8*)&sp2c[sr][cb + 8] = rP1;
    if (tid < 64) smask[tid] = rmask;
    // --- issue next tile's global loads (overlap with compute below)
    if (kt + 1 < TKV / 64) load_tile(kt + 1);
    __syncthreads();

    // --- S^T = K.Q^T (split bf16: 3 terms)
    f32x4 st[4];
    #pragma unroll
    for (int mf = 0; mf < 4; mf++) st[mf] = (f32x4){0.f, 0.f, 0.f, 0.f};
    __builtin_amdgcn_s_setprio(1);
    #pragma unroll
    for (int mf = 0; mf < 4; mf++) {
      #pragma unroll
      for (int ks = 0; ks < 2; ks++) {
        bf16x8 kh = *(const bf16x8*)&sKh[(mf * 8 + ks * 4 + g) * 128 + fr * 8];
        bf16x8 kl = *(const bf16x8*)&sKl[(mf * 8 + ks * 4 + g) * 128 + fr * 8];
        st[mf] = __builtin_amdgcn_mfma_f32_16x16x32_bf16(kh, qh[ks], st[mf], 0, 0, 0);
        st[mf] = __builtin_amdgcn_mfma_f32_16x16x32_bf16(kh, ql[ks], st[mf], 0, 0, 0);
        st[mf] = __builtin_amdgcn_mfma_f32_16x16x32_bf16(kl, qh[ks], st[mf], 0, 0, 0);
      }
    }
    __builtin_amdgcn_s_setprio(0);

    // --- bias + mask + online softmax (q = fr per lane; kj = mf*16 + g*4 + rr)
    const int dq = q0 + qloc - k0 + 1023;
    const ushort_t* c2prow = &sc2p[qloc][0];
    float pv[4][4];
    float lmax = NEG_INF;
    #pragma unroll
    for (int mf = 0; mf < 4; mf++) {
      #pragma unroll
      for (int rr = 0; rr < 4; rr++) {
        int kj = mf * 16 + g * 4 + rr;
        int tbi = stab[dq - kj];
        float v = st[mf][rr] * inv_s + (bf2f(c2prow[tbi]) + bf2f(sp2c[kj][tbi]));
        v = smask[kj] ? NEG_INF : v;
        pv[mf][rr] = v;
        lmax = fmaxf(lmax, v);
      }
    }
    lmax = fmaxf(lmax, __shfl_xor(lmax, 16));
    lmax = fmaxf(lmax, __shfl_xor(lmax, 32));
    // --- T13: skip rescale when running max did not grow
    if (!__all(lmax <= m_run)) {
      float mnew = fmaxf(m_run, lmax);
      float fac = __expf(m_run - mnew);
      m_run = mnew;
      l_run *= fac;
      float facr[4];
      #pragma unroll
      for (int rr = 0; rr < 4; rr++) facr[rr] = __shfl(fac, g * 4 + rr);
      #pragma unroll
      for (int nf = 0; nf < 4; nf++)
        #pragma unroll
        for (int rr = 0; rr < 4; rr++) acc[nf][rr] *= facr[rr];
    }
    float psum = 0.f;
    #pragma unroll
    for (int mf = 0; mf < 4; mf++)
      #pragma unroll
      for (int rr = 0; rr < 4; rr++) {
        float e = __expf(pv[mf][rr] - m_run);
        pv[mf][rr] = e;
        psum += e;
      }
    psum += __shfl_xor(psum, 16);
    psum += __shfl_xor(psum, 32);
    l_run += psum;

    // --- build P A-fragments via shfl gather
    bf16x8 pa[2];
    #pragma unroll
    for (int ks = 0; ks < 2; ks++) {
      bf16x8 t;
      #pragma unroll
      for (int j = 0; j < 8; j++) {
        int src = ((2 * (g & 1) + (j >> 2)) << 4) | fr;
        float v0 = __shfl(pv[2 * ks][j & 3], src);
        float v1 = __shfl(pv[2 * ks + 1][j & 3], src);
        float pvv = (g >> 1) ? v1 : v0;
        t[j] = (short)bf16rn(pvv);
      }
      pa[ks] = t;
    }

    // --- ctx += P.V (V split hi+lo)
    __builtin_amdgcn_s_setprio(1);
    #pragma unroll
    for (int nf = 0; nf < 4; nf++) {
      #pragma unroll
      for (int ks = 0; ks < 2; ks++) {
        bf16x8 vh = *(const bf16x8*)&sVh[(nf * 8 + ks * 4 + g) * 128 + fr * 8];
        bf16x8 vl = *(const bf16x8*)&sVl[(nf * 8 + ks * 4 + g) * 128 + fr * 8];
        acc[nf] = __builtin_amdgcn_mfma_f32_16x16x32_bf16(pa[ks], vh, acc[nf], 0, 0, 0);
        acc[nf] = __builtin_amdgcn_mfma_f32_16x16x32_bf16(pa[ks], vl, acc[nf], 0, 0, 0);
      }
    }
    __builtin_amdgcn_s_setprio(0);
  }

  // --- epilogue
  float invl[4];
  #pragma unroll
  for (int rr = 0; rr < 4; rr++) invl[rr] = 1.0f / __shfl(l_run, g * 4 + rr);
  #pragma unroll
  for (int nf = 0; nf < 4; nf++) {
    #pragma unroll
    for (int rr = 0; rr < 4; rr++) {
      int qrow = q0 + wid * 16 + g * 4 + rr;
      int dcol = h * HD + nf * 16 + fr;
      ctx[((size_t)b * TQ + qrow) * D + dcol] = acc[nf][rr] * invl[rr];
    }
  }
}

extern "C" void kernel_launch(void* const* d_in, const int* in_sizes, int n_in,
                              void* d_out, int out_size, void* d_ws, size_t ws_size,
                              hipStream_t stream) {
  const float* query = (const float*)d_in[0];
  const float* kv    = (const float*)d_in[1];
  const float* Wq  = (const float*)d_in[2];   const float* bq  = (const float*)d_in[3];
  const float* Wk  = (const float*)d_in[4];   const float* bk  = (const float*)d_in[5];
  const float* Wv  = (const float*)d_in[6];   const float* bv  = (const float*)d_in[7];
  const float* Wo  = (const float*)d_in[8];   const float* bo  = (const float*)d_in[9];
  const float* Wpk = (const float*)d_in[10];  const float* bpk = (const float*)d_in[11];
  const float* Wpq = (const float*)d_in[12];  const float* bpq = (const float*)d_in[13];
  const float* rel_emb = (const float*)d_in[14];
  const float* ln_g = (const float*)d_in[15];
  const float* ln_b = (const float*)d_in[16];
  const unsigned char* amask = (const unsigned char*)d_in[17];

  float* ws = (float*)d_ws;
  float* qbuf   = ws + QF_OFF;
  float* ctxbuf = ws + CTX_OFF;
  float* rebuf  = ws + RE_OFF;
  float* poskbuf = ws + POSK_OFF;
  float* posqbuf = ws + POSQ_OFF;
  ushort_t* sbase = (ushort_t*)((char*)d_ws + SHORT_BASE_BYTES);
  ushort_t* c2pbuf = sbase + C2P_S;
  ushort_t* p2cbuf = sbase + P2C_S;
  ushort_t* KH  = sbase + KH_S;
  ushort_t* KL  = sbase + KL_S;
  ushort_t* VTH = sbase + VTH_S;
  ushort_t* VTL = sbase + VTL_S;
  unsigned char* tab = (unsigned char*)d_ws + TAB_OFF_BYTES;

  // 1. LayerNorm of rel_emb + bucket table
  ln_kernel<<<64, 256, 0, stream>>>(rel_emb, ln_g, ln_b, rebuf);
  tab_kernel<<<8, 256, 0, stream>>>(tab);
  // 2. positional projections (64 x 1024 @ 1024^2), z-fused
  gemm_bias_pos<<<dim3(16, 1, 2), 256, 0, stream>>>(rebuf, Wpk, bpk, poskbuf,
                                                    Wpq, bpq, posqbuf, 64, 1024, 1024);
  // 3. Q/K/V projections fused; Q f32, K bf16 hi/lo, V bf16 hi/lo transposed
  gemm_split<<<dim3(16, 16, 3), 256, 0, stream>>>(
      query, kv, kv,  Wq, Wk, Wv,  bq, bk, bv,
      qbuf, KH, KL, VTH, VTL, 2048, 1024, 1024);
  // 4. c2p / p2c (z-fused, bf16 out, pre-scaled by 1/sqrt(128))
  relproj_kernel<<<dim3(16, 32, 2), 256, 0, stream>>>(
      qbuf, poskbuf, c2pbuf, KH, KL, posqbuf, p2cbuf);
  // 5. MFMA flash attention (XCD-swizzled)
  attn_mfma<<<dim3(16, 32), 256, 0, stream>>>(qbuf, KH, KL, VTH, VTL,
                                              c2pbuf, p2cbuf, amask, tab, ctxbuf);
  // 6. output projection -> d_out (z=0 f32 path)
  gemm_split<<<dim3(16, 16, 1), 256, 0, stream>>>(
      ctxbuf, ctxbuf, ctxbuf,  Wo, Wo, Wo,  bo, bo, bo,
      (float*)d_out, nullptr, nullptr, nullptr, nullptr, 2048, 1024, 1024);
}